// Round 2
// baseline (447.951 us; speedup 1.0000x reference)
//
#include <hip/hip_runtime.h>
#include <math.h>

// B=4096, K=64, D=128 (fp32). Embedding row = 128 floats = 32 float4 = 512 B.
// Kernel 1: one 32-lane half-wave per (b,k) negative pair. Lane l holds
//           float4 element l of the row -> each row gather is one coalesced
//           512 B global_load_dwordx4 across the half-wave. No loops, no LDS:
//           pure TLP latency hiding (131072 waves, ~128 waves/SIMD of work).
// Kernel 2: one wave64 per b: min over out_dist[b,:] + positive distance
//           (float2 per lane across 64 lanes).

__device__ __forceinline__ float halfwave_sum(float v) {
    // xor offsets 1..16 stay inside each 32-lane half of the wave64.
    #pragma unroll
    for (int off = 16; off; off >>= 1) v += __shfl_xor(v, off);
    return v;
}

__global__ __launch_bounds__(256) void neg_dist_kernel(
    const int* __restrict__ pairs,     // (B,2)
    const int* __restrict__ neg_samp,  // (B,K) flat
    const int* __restrict__ neg_art,   // (B,K)
    const int* __restrict__ neg_alb,   // (B,K)
    const float4* __restrict__ Wu,     // (N_USERS, 32)
    const float4* __restrict__ Wi,     // (N_ITEMS, 32)
    const float4* __restrict__ Wart,   // (N_ARTISTS, 32)
    const float4* __restrict__ Walb,   // (N_ALBUMS, 32)
    float* __restrict__ out_dist,      // (B,K) flat
    int total, int Kn)
{
    const int lane = threadIdx.x & 31;
    const int g    = blockIdx.x * 8 + (threadIdx.x >> 5); // flat (b,k) index
    if (g >= total) return;
    const int b = g / Kn; // Kn=64 -> compiler emits shift/magic-mul

    // All three neg-index loads are independent; issue together.
    const int ii = neg_samp[g];
    const int ia = neg_art [g];
    const int il = neg_alb [g];
    const int ui = pairs[2 * b];

    const float4 u = Wu  [(size_t)ui * 32 + lane];
    const float4 a = Wi  [(size_t)ii * 32 + lane];
    const float4 r = Wart[(size_t)ia * 32 + lane];
    const float4 l = Walb[(size_t)il * 32 + lane];

    const float inv3 = 1.0f / 3.0f;
    const float dx = u.x - (a.x + r.x + l.x) * inv3;
    const float dy = u.y - (a.y + r.y + l.y) * inv3;
    const float dz = u.z - (a.z + r.z + l.z) * inv3;
    const float dw = u.w - (a.w + r.w + l.w) * inv3;
    float acc = dx * dx + dy * dy + dz * dz + dw * dw;
    acc = halfwave_sum(acc);
    if (lane == 0) out_dist[g] = acc;
}

__global__ __launch_bounds__(64) void pos_min_kernel(
    const int* __restrict__ pairs,
    const int* __restrict__ pos_art,
    const int* __restrict__ pos_alb,
    const float2* __restrict__ Wu,     // (N_USERS, 64) as float2
    const float2* __restrict__ Wi,
    const float2* __restrict__ Wart,
    const float2* __restrict__ Walb,
    const float* __restrict__ out_dist, // (B,K)
    float* __restrict__ out_pos,        // (B,)
    float* __restrict__ out_min,        // (B,)
    int Kn)
{
    const int b    = blockIdx.x;
    const int lane = threadIdx.x; // 0..63, one wave

    // --- min over the K=64 negative distances ---
    float m = out_dist[b * Kn + lane];
    #pragma unroll
    for (int off = 32; off; off >>= 1) m = fminf(m, __shfl_xor(m, off));
    if (lane == 0) out_min[b] = m;

    // --- positive distance: lane holds float2 element (2 floats) of D=128 ---
    const int ui = pairs[2 * b];
    const int ii = pairs[2 * b + 1];
    const int ia = pos_art[b];
    const int il = pos_alb[b];
    const float2 u = Wu  [(size_t)ui * 64 + lane];
    const float2 a = Wi  [(size_t)ii * 64 + lane];
    const float2 r = Wart[(size_t)ia * 64 + lane];
    const float2 l = Walb[(size_t)il * 64 + lane];
    const float inv3 = 1.0f / 3.0f;
    const float dx = u.x - (a.x + r.x + l.x) * inv3;
    const float dy = u.y - (a.y + r.y + l.y) * inv3;
    float acc = dx * dx + dy * dy;
    #pragma unroll
    for (int off = 32; off; off >>= 1) acc += __shfl_xor(acc, off);
    if (lane == 0) out_pos[b] = acc;
}

extern "C" void kernel_launch(void* const* d_in, const int* in_sizes, int n_in,
                              void* d_out, int out_size, void* d_ws, size_t ws_size,
                              hipStream_t stream) {
    const int* pairs    = (const int*)d_in[0];
    const int* pos_art  = (const int*)d_in[1];
    const int* pos_alb  = (const int*)d_in[2];
    const int* neg_samp = (const int*)d_in[3];
    const int* neg_art  = (const int*)d_in[4];
    const int* neg_alb  = (const int*)d_in[5];
    // d_in[6] titles, d_in[7] titles_len: unused by the reference math.
    const float* Wu   = (const float*)d_in[8];
    const float* Wi   = (const float*)d_in[9];
    const float* Wart = (const float*)d_in[10];
    const float* Walb = (const float*)d_in[11];

    const int Bn = in_sizes[1];            // 4096
    const int Kn = in_sizes[3] / Bn;       // 64
    const int total = Bn * Kn;             // 262144

    float* out      = (float*)d_out;
    float* out_pos  = out;                         // (B,)
    float* out_dist = out + Bn;                    // (B,K)
    float* out_min  = out + Bn + (size_t)Bn * Kn;  // (B,)

    const int blocks1 = (total + 7) / 8;   // 8 half-waves per 256-thread block
    neg_dist_kernel<<<blocks1, 256, 0, stream>>>(
        pairs, neg_samp, neg_art, neg_alb,
        (const float4*)Wu, (const float4*)Wi, (const float4*)Wart, (const float4*)Walb,
        out_dist, total, Kn);

    pos_min_kernel<<<Bn, 64, 0, stream>>>(
        pairs, pos_art, pos_alb,
        (const float2*)Wu, (const float2*)Wi, (const float2*)Wart, (const float2*)Walb,
        out_dist, out_pos, out_min, Kn);
}

// Round 3
// 438.331 us; speedup vs baseline: 1.0219x; 1.0219x over previous
//
#include <hip/hip_runtime.h>
#include <math.h>

// B=4096, K=64, D=128 (fp32). Row = 128 floats = 32 float4 = 512 B.
// One block per b (4096 blocks x 256 threads = 8 half-waves).
// Half-wave hw owns k = hw*8 .. hw*8+7, processed in 2 batches of 4 with all
// 12 row-gathers of a batch in flight (MLP). u row loaded once per block into
// registers. Wi gathers are nontemporal (256 MB zero-reuse stream must not
// evict the reusable Wart/Walb/Wu working set from L2/L3).

typedef float vf4 __attribute__((ext_vector_type(4)));

__device__ __forceinline__ float halfwave_sum(float v) {
    // xor offsets 1..16 stay inside each 32-lane half of the wave64.
    #pragma unroll
    for (int off = 16; off; off >>= 1) v += __shfl_xor(v, off);
    return v;
}

__device__ __forceinline__ float dist_sq(vf4 u, vf4 a, vf4 r, vf4 l) {
    const float inv3 = 1.0f / 3.0f;
    const float dx = u.x - (a.x + r.x + l.x) * inv3;
    const float dy = u.y - (a.y + r.y + l.y) * inv3;
    const float dz = u.z - (a.z + r.z + l.z) * inv3;
    const float dw = u.w - (a.w + r.w + l.w) * inv3;
    float acc = dx * dx + dy * dy + dz * dz + dw * dw;
    return halfwave_sum(acc);
}

__global__ __launch_bounds__(256) void cml_fused_kernel(
    const int* __restrict__ pairs,     // (B,2)
    const int* __restrict__ pos_art,   // (B,)
    const int* __restrict__ pos_alb,   // (B,)
    const int* __restrict__ neg_samp,  // (B,K)
    const int* __restrict__ neg_art,   // (B,K)
    const int* __restrict__ neg_alb,   // (B,K)
    const vf4* __restrict__ Wu,        // (N_USERS, 32)
    const vf4* __restrict__ Wi,        // (N_ITEMS, 32)
    const vf4* __restrict__ Wart,      // (N_ARTISTS, 32)
    const vf4* __restrict__ Walb,      // (N_ALBUMS, 32)
    float* __restrict__ out_pos,       // (B,)
    float* __restrict__ out_dist,      // (B,K)
    float* __restrict__ out_min,       // (B,)
    int Kn)
{
    const int b    = blockIdx.x;
    const int tid  = threadIdx.x;
    const int lane = tid & 31;   // lane within half-wave
    const int hw   = tid >> 5;   // half-wave id, 0..7

    __shared__ float s_min[8];

    // User row: lane l holds float4 element l. One 512B coalesced gather,
    // reused (in registers) across all 8 k's of this half-wave.
    const int ui = pairs[2 * b];
    const vf4 u = Wu[(size_t)ui * 32 + lane];

    // Positive distance: half-wave 0 only.
    if (hw == 0) {
        const int ii = pairs[2 * b + 1];
        const int ia = pos_art[b];
        const int il = pos_alb[b];
        const vf4 a = Wi  [(size_t)ii * 32 + lane];
        const vf4 r = Wart[(size_t)ia * 32 + lane];
        const vf4 l = Walb[(size_t)il * 32 + lane];
        const float d = dist_sq(u, a, r, l);
        if (lane == 0) out_pos[b] = d;
    }

    // My half-wave's 8 indices per table: lanes 0..7 load 8 consecutive ints
    // (one 32B coalesced load each), then broadcast with __shfl width=32.
    const int kbase = b * Kn + hw * 8;
    int v_samp = 0, v_art = 0, v_alb = 0;
    if (lane < 8) {
        v_samp = neg_samp[kbase + lane];
        v_art  = neg_art [kbase + lane];
        v_alb  = neg_alb [kbase + lane];
    }

    float m = INFINITY;

    #pragma unroll
    for (int batch = 0; batch < 2; ++batch) {
        vf4 A[4], R[4], L[4];
        // Issue all 12 gathers of the batch back-to-back (MLP).
        #pragma unroll
        for (int j = 0; j < 4; ++j) {
            const int jj = batch * 4 + j;
            const int ii = __shfl(v_samp, jj, 32);
            const int ia = __shfl(v_art,  jj, 32);
            const int il = __shfl(v_alb,  jj, 32);
            // Wi: 256MB zero-reuse stream -> nontemporal.
            A[j] = __builtin_nontemporal_load(&Wi[(size_t)ii * 32 + lane]);
            R[j] = Wart[(size_t)ia * 32 + lane];
            L[j] = Walb[(size_t)il * 32 + lane];
        }
        float myd = 0.0f;
        #pragma unroll
        for (int j = 0; j < 4; ++j) {
            const float d = dist_sq(u, A[j], R[j], L[j]); // broadcast in half-wave
            m = fminf(m, d);
            if (lane == j) myd = d; // lane j keeps distance j
        }
        // One coalesced 16B (4-lane) store per half-wave per batch.
        if (lane < 4) out_dist[kbase + batch * 4 + lane] = myd;
    }

    if (lane == 0) s_min[hw] = m;
    __syncthreads();

    if (tid == 0) {
        float mm = s_min[0];
        #pragma unroll
        for (int i = 1; i < 8; ++i) mm = fminf(mm, s_min[i]);
        out_min[b] = mm;
    }
}

extern "C" void kernel_launch(void* const* d_in, const int* in_sizes, int n_in,
                              void* d_out, int out_size, void* d_ws, size_t ws_size,
                              hipStream_t stream) {
    const int* pairs    = (const int*)d_in[0];
    const int* pos_art  = (const int*)d_in[1];
    const int* pos_alb  = (const int*)d_in[2];
    const int* neg_samp = (const int*)d_in[3];
    const int* neg_art  = (const int*)d_in[4];
    const int* neg_alb  = (const int*)d_in[5];
    // d_in[6] titles, d_in[7] titles_len: unused by the reference math.
    const vf4* Wu   = (const vf4*)d_in[8];
    const vf4* Wi   = (const vf4*)d_in[9];
    const vf4* Wart = (const vf4*)d_in[10];
    const vf4* Walb = (const vf4*)d_in[11];

    const int Bn = in_sizes[1];            // 4096
    const int Kn = in_sizes[3] / Bn;       // 64

    float* out      = (float*)d_out;
    float* out_pos  = out;                         // (B,)
    float* out_dist = out + Bn;                    // (B,K)
    float* out_min  = out + Bn + (size_t)Bn * Kn;  // (B,)

    cml_fused_kernel<<<Bn, 256, 0, stream>>>(
        pairs, pos_art, pos_alb, neg_samp, neg_art, neg_alb,
        Wu, Wi, Wart, Walb, out_pos, out_dist, out_min, Kn);
}